// Round 16
// baseline (98.890 us; speedup 1.0000x reference)
//
#include <hip/hip_runtime.h>
#include <hip/hip_bf16.h>
#include <stdint.h>

#define M_DIM 2048
#define K_DIM 4096
#define N_DIM 4096

typedef __attribute__((ext_vector_type(8))) short short8;
typedef __attribute__((ext_vector_type(4))) float f32x4;

#define MFMA __builtin_amdgcn_mfma_f32_16x16x32_bf16

// RNE float -> bf16, packed pair
__device__ __forceinline__ uint32_t bf16pk(float a, float b) {
  uint32_t ua = __float_as_uint(a);
  ua = (ua + 0x7FFFu + ((ua >> 16) & 1u)) >> 16;
  uint32_t ub = __float_as_uint(b);
  ub = (ub + 0x7FFFu + ((ub >> 16) & 1u)) >> 16;
  return ua | (ub << 16);
}

// ---------------------------------------------------------------------------
// Image layout: BK=32 steps, 8KB tiles, [k8-slot 0..3][row 0..127][16B].
//  xImg[mt 0..15][step 0..127]  (16.78 MB)
//  wImg[nt 0..31][step 0..127]  (33.55 MB)
// Verified R6-R15. Fragment reads are 256B-contiguous per 16-lane group ->
// perfectly coalesced as GLOBAL loads too (4 x 64B segments per dwordx4).
// ---------------------------------------------------------------------------

// Merged prepass (R8-verified bodies): grid 3072 x 256.
__global__ void __launch_bounds__(256) prep_kernel(const float* __restrict__ x,
                                                   const uint32_t* __restrict__ qweight,
                                                   const uint32_t* __restrict__ qzeros,
                                                   const float* __restrict__ scales,
                                                   char* __restrict__ xImg,
                                                   char* __restrict__ wImg) {
  const int tid = threadIdx.x;
  if (blockIdx.x < 1024) {
    const int bid = blockIdx.x;
    const int mt = bid >> 6, ktp = bid & 63;
    const int row = tid & 127, sh = tid >> 7;
    const int s = ktp * 2 + sh;
    const float* src = x + (size_t)(mt * 128 + row) * K_DIM + s * 32;
    char* dst = xImg + (size_t)(mt * 128 + s) * 8192 + row * 16;
#pragma unroll
    for (int slot = 0; slot < 4; ++slot) {
      float4 f0 = *(const float4*)(src + slot * 8);
      float4 f1 = *(const float4*)(src + slot * 8 + 4);
      uint4 pk;
      pk.x = bf16pk(f0.x, f0.y);
      pk.y = bf16pk(f0.z, f0.w);
      pk.z = bf16pk(f1.x, f1.y);
      pk.w = bf16pk(f1.z, f1.w);
      *(uint4*)(dst + slot * 2048) = pk;
    }
  } else {
    const int bid = blockIdx.x - 1024;
    const int nt = bid >> 6, ktp = bid & 63;
    const int n = tid & 127, sh = tid >> 7;
    const int s = ktp * 2 + sh;
    const int g = ktp >> 1;                    // group = 128 k = 4 steps
    const int gn = nt * 128 + n;
    uint32_t zq = qzeros[g * (N_DIM / 8) + (gn >> 3)];
    const int z = (int)((zq >> ((gn & 7) * 4)) & 15u) + 1;
    const float s_ = scales[g * N_DIM + gn];
    char* dst = wImg + (size_t)(nt * 128 + s) * 8192 + n * 16;
#pragma unroll
    for (int slot = 0; slot < 4; ++slot) {
      uint32_t q = qweight[(size_t)(s * 4 + slot) * N_DIM + gn];
      float f[8];
#pragma unroll
      for (int v = 0; v < 8; ++v) {
        int w = (int)((q >> (4 * v)) & 15u);
        f[v] = (float)(w - z) * s_;            // exact int sub, cvt, mul
      }
      uint4 pk;
      pk.x = bf16pk(f[0], f[1]);
      pk.y = bf16pk(f[2], f[3]);
      pk.z = bf16pk(f[4], f[5]);
      pk.w = bf16pk(f[6], f[7]);
      *(uint4*)(dst + slot * 2048) = pk;
    }
  }
}

// ---------------------------------------------------------------------------
// GEMM: FREE-RUN REGISTER GEMM (flatmm-style). No LDS, no barriers, no
// cross-wave coupling in the K-loop.
//
// Diagnosis R8-R15: every LDS-staged variant pays LDS-port + barrier
// lockstep; all land 67-80us. Here each wave owns a 128x64 output tile and
// reads A/B fragments straight from L2 into registers (the pre-swizzled
// image makes frag reads 256B-contiguous per 16-lane group = perfectly
// coalesced). One-step register prefetch hides L2 latency (issued ~620cy
// before use); compiler emits per-use counted vmcnt.
//
// Occupancy: 1024 waves = 256 blocks x 4 = 4 waves/CU (1/SIMD); matrix
// pipe per SIMD ~fully owned by its wave: floor 128 steps x 620cy = 33us.
// BW/CU/step: A 8KB (4 waves read SAME rows -> L1-served) + B 16KB from
// L2 = 39 B/cyc < 56 L2 budget -> MFMA-bound.
// Block = 4 waves sharing mb (A rows shared); XCD owns 2 nbq (4MB B = L2).
// ---------------------------------------------------------------------------
__global__ void __launch_bounds__(256, 1) gemm_kernel(const char* __restrict__ xImg,
                                                      const char* __restrict__ wImg,
                                                      const float* __restrict__ bias,
                                                      float* __restrict__ out) {
  const int tid = threadIdx.x;
  const int lane = tid & 63, wv = tid >> 6;    // wave = one 64-col slice
  const int lr = lane & 15, lk = lane >> 4;

  // 256 blocks = 16 mb x 16 nbq; XCD-chunked (256%8==0): xcd owns 2 nbq.
  const int bid = blockIdx.x;
  const int xcd = bid & 7, local = bid >> 3;   // local 0..31
  const int nbq = xcd * 2 + (local & 1);       // 0..15
  const int mb = local >> 1;                   // 0..15

  f32x4 acc[8][4];
#pragma unroll
  for (int i = 0; i < 8; ++i)
#pragma unroll
    for (int j = 0; j < 4; ++j) acc[i][j] = f32x4{0.f, 0.f, 0.f, 0.f};

  const char* aT = xImg + (size_t)mb * 128 * 8192;            // + t*8192
  const int nt = nbq * 2 + (wv >> 1);                         // 128-col panel
  const int colIn = (wv & 1) * 64;                            // 64-col slice
  const char* bT = wImg + (size_t)nt * 128 * 8192;            // + t*8192

  int aoff[8], boff[4];
#pragma unroll
  for (int i = 0; i < 8; ++i) aoff[i] = lk * 2048 + (i * 16 + lr) * 16;
#pragma unroll
  for (int j = 0; j < 4; ++j) boff[j] = lk * 2048 + (colIn + j * 16 + lr) * 16;

  // prologue: load step 0 fragments
  short8 ca0 = *(const short8*)(aT + aoff[0]);
  short8 ca1 = *(const short8*)(aT + aoff[1]);
  short8 ca2 = *(const short8*)(aT + aoff[2]);
  short8 ca3 = *(const short8*)(aT + aoff[3]);
  short8 ca4 = *(const short8*)(aT + aoff[4]);
  short8 ca5 = *(const short8*)(aT + aoff[5]);
  short8 ca6 = *(const short8*)(aT + aoff[6]);
  short8 ca7 = *(const short8*)(aT + aoff[7]);
  short8 cb0 = *(const short8*)(bT + boff[0]);
  short8 cb1 = *(const short8*)(bT + boff[1]);
  short8 cb2 = *(const short8*)(bT + boff[2]);
  short8 cb3 = *(const short8*)(bT + boff[3]);

#pragma unroll 2
  for (int t = 0; t < 128; ++t) {
    // prefetch step t+1 into the alternate register set (renamed by unroll)
    short8 na0, na1, na2, na3, na4, na5, na6, na7, nb0, nb1, nb2, nb3;
    if (t < 127) {
      const char* aS = aT + (size_t)(t + 1) * 8192;
      const char* bS = bT + (size_t)(t + 1) * 8192;
      na0 = *(const short8*)(aS + aoff[0]);
      na1 = *(const short8*)(aS + aoff[1]);
      na2 = *(const short8*)(aS + aoff[2]);
      na3 = *(const short8*)(aS + aoff[3]);
      na4 = *(const short8*)(aS + aoff[4]);
      na5 = *(const short8*)(aS + aoff[5]);
      na6 = *(const short8*)(aS + aoff[6]);
      na7 = *(const short8*)(aS + aoff[7]);
      nb0 = *(const short8*)(bS + boff[0]);
      nb1 = *(const short8*)(bS + boff[1]);
      nb2 = *(const short8*)(bS + boff[2]);
      nb3 = *(const short8*)(bS + boff[3]);
    }

    acc[0][0] = MFMA(ca0, cb0, acc[0][0], 0, 0, 0);
    acc[1][0] = MFMA(ca1, cb0, acc[1][0], 0, 0, 0);
    acc[2][0] = MFMA(ca2, cb0, acc[2][0], 0, 0, 0);
    acc[3][0] = MFMA(ca3, cb0, acc[3][0], 0, 0, 0);
    acc[4][0] = MFMA(ca4, cb0, acc[4][0], 0, 0, 0);
    acc[5][0] = MFMA(ca5, cb0, acc[5][0], 0, 0, 0);
    acc[6][0] = MFMA(ca6, cb0, acc[6][0], 0, 0, 0);
    acc[7][0] = MFMA(ca7, cb0, acc[7][0], 0, 0, 0);
    acc[0][1] = MFMA(ca0, cb1, acc[0][1], 0, 0, 0);
    acc[1][1] = MFMA(ca1, cb1, acc[1][1], 0, 0, 0);
    acc[2][1] = MFMA(ca2, cb1, acc[2][1], 0, 0, 0);
    acc[3][1] = MFMA(ca3, cb1, acc[3][1], 0, 0, 0);
    acc[4][1] = MFMA(ca4, cb1, acc[4][1], 0, 0, 0);
    acc[5][1] = MFMA(ca5, cb1, acc[5][1], 0, 0, 0);
    acc[6][1] = MFMA(ca6, cb1, acc[6][1], 0, 0, 0);
    acc[7][1] = MFMA(ca7, cb1, acc[7][1], 0, 0, 0);
    acc[0][2] = MFMA(ca0, cb2, acc[0][2], 0, 0, 0);
    acc[1][2] = MFMA(ca1, cb2, acc[1][2], 0, 0, 0);
    acc[2][2] = MFMA(ca2, cb2, acc[2][2], 0, 0, 0);
    acc[3][2] = MFMA(ca3, cb2, acc[3][2], 0, 0, 0);
    acc[4][2] = MFMA(ca4, cb2, acc[4][2], 0, 0, 0);
    acc[5][2] = MFMA(ca5, cb2, acc[5][2], 0, 0, 0);
    acc[6][2] = MFMA(ca6, cb2, acc[6][2], 0, 0, 0);
    acc[7][2] = MFMA(ca7, cb2, acc[7][2], 0, 0, 0);
    acc[0][3] = MFMA(ca0, cb3, acc[0][3], 0, 0, 0);
    acc[1][3] = MFMA(ca1, cb3, acc[1][3], 0, 0, 0);
    acc[2][3] = MFMA(ca2, cb3, acc[2][3], 0, 0, 0);
    acc[3][3] = MFMA(ca3, cb3, acc[3][3], 0, 0, 0);
    acc[4][3] = MFMA(ca4, cb3, acc[4][3], 0, 0, 0);
    acc[5][3] = MFMA(ca5, cb3, acc[5][3], 0, 0, 0);
    acc[6][3] = MFMA(ca6, cb3, acc[6][3], 0, 0, 0);
    acc[7][3] = MFMA(ca7, cb3, acc[7][3], 0, 0, 0);

    if (t < 127) {
      ca0 = na0; ca1 = na1; ca2 = na2; ca3 = na3;
      ca4 = na4; ca5 = na5; ca6 = na6; ca7 = na7;
      cb0 = nb0; cb1 = nb1; cb2 = nb2; cb3 = nb3;
    }
  }

  // epilogue: direct store (full K per wave). C/D map col=lane&15,
  // row=(lane>>4)*4+reg (verified R0-R15).
  const int colB = nbq * 256 + wv * 64 + lr;
#pragma unroll
  for (int j = 0; j < 4; ++j) {
    int col = colB + j * 16;
    float bj = bias[col];
#pragma unroll
    for (int i = 0; i < 8; ++i) {
      int row = mb * 128 + i * 16 + lk * 4;
#pragma unroll
      for (int r = 0; r < 4; ++r)
        out[(size_t)(row + r) * N_DIM + col] = acc[i][j][r] + bj;
    }
  }
}

// ---------------------------------------------------------------------------
// Fallback (workspace too small)
// ---------------------------------------------------------------------------
__global__ void fallback_kernel(const float* __restrict__ x, const uint32_t* __restrict__ qweight,
                                const uint32_t* __restrict__ qzeros, const float* __restrict__ scales,
                                const float* __restrict__ bias, float* __restrict__ out) {
  __shared__ float xs[16][17];
  __shared__ float ws[16][17];
  int tx = threadIdx.x, ty = threadIdx.y;
  int col = blockIdx.x * 16 + tx;
  int row = blockIdx.y * 16 + ty;
  float acc = 0.f;
  for (int k0 = 0; k0 < K_DIM; k0 += 16) {
    xs[ty][tx] = x[(size_t)row * K_DIM + k0 + tx];
    int k = k0 + ty;
    int g = k >> 7;
    uint32_t q = qweight[(size_t)(k >> 3) * N_DIM + col];
    int w = (int)((q >> ((k & 7) * 4)) & 15u);
    uint32_t zq = qzeros[g * (N_DIM / 8) + (col >> 3)];
    int z = (int)((zq >> ((col & 7) * 4)) & 15u) + 1;
    ws[ty][tx] = (float)(w - z) * scales[g * N_DIM + col];
    __syncthreads();
#pragma unroll
    for (int kk = 0; kk < 16; ++kk) acc += xs[ty][kk] * ws[kk][tx];
    __syncthreads();
  }
  out[(size_t)row * N_DIM + col] = acc + bias[col];
}

extern "C" void kernel_launch(void* const* d_in, const int* in_sizes, int n_in,
                              void* d_out, int out_size, void* d_ws, size_t ws_size,
                              hipStream_t stream) {
  const float* x = (const float*)d_in[0];
  const uint32_t* qweight = (const uint32_t*)d_in[1];
  const uint32_t* qzeros = (const uint32_t*)d_in[2];
  const float* scales = (const float*)d_in[3];
  // d_in[4] = g_idx (== arange(K)//128, folded into index math)
  const float* bias = (const float*)d_in[5];
  float* out = (float*)d_out;

  const size_t X_IMG = (size_t)16 * 128 * 8192;   // 16.78 MB
  const size_t W_IMG = (size_t)32 * 128 * 8192;   // 33.55 MB

  if (ws_size >= X_IMG + W_IMG) {
    char* xImg = (char*)d_ws;
    char* wImg = (char*)d_ws + X_IMG;
    prep_kernel<<<3072, 256, 0, stream>>>(x, qweight, qzeros, scales, xImg, wImg);
    gemm_kernel<<<256, 256, 0, stream>>>(xImg, wImg, bias, out);
  } else {
    fallback_kernel<<<dim3(N_DIM / 16, M_DIM / 16), dim3(16, 16), 0, stream>>>(
        x, qweight, qzeros, scales, bias, out);
  }
}